// Round 3
// baseline (946.914 us; speedup 1.0000x reference)
//
#include <hip/hip_runtime.h>
#include <hip/hip_bf16.h>
#include <string.h>

namespace {

constexpr int Bc  = 2;
constexpr int Nc  = 16384;
constexpr int Rc  = 2048;
constexpr int CAc = 128;
constexpr int CSc = 256;
constexpr int CPc = 16;
constexpr int Hc  = 4;
constexpr int WQc = 32;
constexpr int WKc = 128;
constexpr int NWc = 512;
constexpr int CHc = 32;
constexpr float EPSf     = 1e-5f;
constexpr float NEG_INF  = -1e8f;
constexpr float QK_SCALE = 0.17677669529663687f;  // 1/sqrt(32)

__device__ __forceinline__ float wsum(float v) {
#pragma unroll
  for (int m = 1; m < 64; m <<= 1) v += __shfl_xor(v, m, 64);
  return v;
}
__device__ __forceinline__ float sigm(float x) { return 1.0f / (1.0f + __expf(-x)); }
__device__ __forceinline__ float f4c(const float4& v, int i) {
  return i == 0 ? v.x : i == 1 ? v.y : i == 2 ? v.z : v.w;
}
__device__ __forceinline__ unsigned pk2(float a, float b) {
  __hip_bfloat16 ha = __float2bfloat16(a), hb = __float2bfloat16(b);
  unsigned short ua, ub;
  memcpy(&ua, &ha, 2); memcpy(&ub, &hb, 2);
  return (unsigned)ua | ((unsigned)ub << 16);
}
__device__ __forceinline__ float unpk(unsigned u, int hi) {
  unsigned short us = hi ? (unsigned short)(u >> 16) : (unsigned short)(u & 0xffff);
  __hip_bfloat16 h;
  memcpy(&h, &us, 2);
  return __bfloat162float(h);
}

// ---------------- K1a: per-res LN (two weighted variants) ----------------
__global__ void k_res_ln(const float* __restrict__ res, const float* __restrict__ a_ln_w,
                         const float* __restrict__ t_ln_w, float* __restrict__ lnA,
                         float* __restrict__ lnT) {
  const int wid = threadIdx.x >> 6, lane = threadIdx.x & 63;
  const int row = blockIdx.x * 4 + wid;  // B*R rows
  const float* r = res + (size_t)row * CSc;
  float x[4], s = 0.f, sq = 0.f;
#pragma unroll
  for (int i = 0; i < 4; ++i) { x[i] = r[lane + 64 * i]; s += x[i]; sq += x[i] * x[i]; }
  s = wsum(s); sq = wsum(sq);
  const float mn = s * (1.0f / CSc);
  const float var = sq * (1.0f / CSc) - mn * mn;
  const float rs = rsqrtf(var + EPSf);
#pragma unroll
  for (int i = 0; i < 4; ++i) {
    const int c = lane + 64 * i;
    const float y = (x[i] - mn) * rs;
    lnA[(size_t)row * CSc + c] = y * a_ln_w[c];
    lnT[(size_t)row * CSc + c] = y * t_ln_w[c];
  }
}

// ---------------- K1b: 6 res GEMMs (K=256 -> 128 cols), gates sigmoid'd ----
__global__ void k_res_gemm(const float* __restrict__ lnA, const float* __restrict__ lnT,
                           const float* __restrict__ res,
                           const float* __restrict__ a_Wg, const float* __restrict__ a_bg,
                           const float* __restrict__ a_Wb,
                           const float* __restrict__ t_Wg, const float* __restrict__ t_bg,
                           const float* __restrict__ t_Wb,
                           const float* __restrict__ sg_W, const float* __restrict__ sg_b,
                           const float* __restrict__ t_Wc, const float* __restrict__ t_bc,
                           float* __restrict__ Ag, float* __restrict__ Ab,
                           float* __restrict__ Tg, float* __restrict__ Tb,
                           float* __restrict__ Sg, float* __restrict__ Tc) {
  __shared__ float tile[32 * CSc];
  const int m = blockIdx.y;
  const float* in = (m < 2) ? lnA : (m < 4) ? lnT : res;
  const float* W  = (m == 0) ? a_Wg : (m == 1) ? a_Wb : (m == 2) ? t_Wg
                  : (m == 3) ? t_Wb : (m == 4) ? sg_W : t_Wc;
  const float* bias = (m == 0) ? a_bg : (m == 2) ? t_bg : (m == 4) ? sg_b
                    : (m == 5) ? t_bc : nullptr;
  const bool sig = (m == 0) || (m == 2) || (m == 4) || (m == 5);
  float* out = (m == 0) ? Ag : (m == 1) ? Ab : (m == 2) ? Tg
             : (m == 3) ? Tb : (m == 4) ? Sg : Tc;
  const int row0 = blockIdx.x * 32;
  const float4* src = (const float4*)(in + (size_t)row0 * CSc);
  float4* dst = (float4*)tile;
#pragma unroll
  for (int k = 0; k < 8; ++k) dst[threadIdx.x + 256 * k] = src[threadIdx.x + 256 * k];
  __syncthreads();
  const int c0 = (threadIdx.x & 31) * 4;
  const int r0 = (threadIdx.x >> 5) * 4;
  float acc[4][4] = {};
  for (int j = 0; j < CSc; j += 4) {
    float4 a[4];
#pragma unroll
    for (int r = 0; r < 4; ++r) a[r] = *(const float4*)&tile[(r0 + r) * CSc + j];
#pragma unroll
    for (int jj = 0; jj < 4; ++jj) {
      const float4 w = *(const float4*)&W[(size_t)(j + jj) * CAc + c0];
#pragma unroll
      for (int r = 0; r < 4; ++r) {
        const float av = f4c(a[r], jj);
        acc[r][0] += av * w.x; acc[r][1] += av * w.y;
        acc[r][2] += av * w.z; acc[r][3] += av * w.w;
      }
    }
  }
  float4 bv = make_float4(0.f, 0.f, 0.f, 0.f);
  if (bias) bv = *(const float4*)&bias[c0];
#pragma unroll
  for (int r = 0; r < 4; ++r) {
    float4 o;
    o.x = acc[r][0] + bv.x; o.y = acc[r][1] + bv.y;
    o.z = acc[r][2] + bv.z; o.w = acc[r][3] + bv.w;
    if (sig) { o.x = sigm(o.x); o.y = sigm(o.y); o.z = sigm(o.z); o.w = sigm(o.w); }
    *(float4*)&out[(size_t)(row0 + r0 + r) * CAc + c0] = o;
  }
}

// ---------------- K2/K5: adaLN over atoms (row LN 128 + gather gate/bias) --
__global__ void k_adaln(const float* __restrict__ in, const int* __restrict__ idxG,
                        const float* __restrict__ G, const float* __restrict__ Bb,
                        float* __restrict__ out) {
  const int wid = threadIdx.x >> 6, lane = threadIdx.x & 63;
  const int row = blockIdx.x * 4 + wid;  // B*N rows
  const int b = row >> 14;
  const float* r = in + (size_t)row * CAc;
  const float x0 = r[lane], x1 = r[lane + 64];
  const float s = wsum(x0 + x1);
  const float sq = wsum(x0 * x0 + x1 * x1);
  const float mn = s * (1.0f / CAc);
  const float var = sq * (1.0f / CAc) - mn * mn;
  const float rs = rsqrtf(var + EPSf);
  const int base = (b * Rc + idxG[row]) * CAc;
  out[(size_t)row * CAc + lane]      = (x0 - mn) * rs * G[base + lane]      + Bb[base + lane];
  out[(size_t)row * CAc + lane + 64] = (x1 - mn) * rs * G[base + lane + 64] + Bb[base + lane + 64];
}

// ---------------- K3: q/kv projection GEMM, W staged in LDS ----------------
__global__ __launch_bounds__(256) void k_qkv2(
    const float* __restrict__ s, const float* __restrict__ q_W,
    const float* __restrict__ q_b, const float* __restrict__ kv_W,
    float* __restrict__ q, float* __restrict__ kv) {
  __shared__ float stile[64 * CAc];   // 32 KB
  __shared__ float wbuf[32 * 132];    // 16.5 KB (pad 132 floats/row)
  const int tid = threadIdx.x;
  const int row0 = blockIdx.x * 64;
  {
    const float4* src = (const float4*)(s + (size_t)row0 * CAc);
    float4* dst = (float4*)stile;
#pragma unroll
    for (int k = 0; k < 8; ++k) dst[tid + 256 * k] = src[tid + 256 * k];
  }
  const int c0 = (tid & 31) * 4;
  const int r0 = (tid >> 5) * 8;
#pragma unroll
  for (int cg = 0; cg < 3; ++cg) {
    const float* W  = (cg == 0) ? q_W : kv_W;
    const int wld   = (cg == 0) ? CAc : 2 * CAc;
    const int woff  = (cg == 2) ? CAc : 0;
    float acc[8][4] = {};
    for (int kc = 0; kc < 4; ++kc) {
      __syncthreads();
#pragma unroll
      for (int u = 0; u < 4; ++u) {
        const int i = tid + 256 * u;          // 1024 float4 = 32x128 floats
        const int rr = i >> 5, cc = i & 31;
        *(float4*)&wbuf[rr * 132 + cc * 4] =
            *(const float4*)&W[(size_t)(kc * 32 + rr) * wld + woff + cc * 4];
      }
      __syncthreads();
      for (int j4 = 0; j4 < 8; ++j4) {
        float4 a[8];
#pragma unroll
        for (int r = 0; r < 8; ++r)
          a[r] = *(const float4*)&stile[(r0 + r) * CAc + kc * 32 + j4 * 4];
#pragma unroll
        for (int jj = 0; jj < 4; ++jj) {
          const float4 w = *(const float4*)&wbuf[(j4 * 4 + jj) * 132 + c0];
#pragma unroll
          for (int r = 0; r < 8; ++r) {
            const float av = f4c(a[r], jj);
            acc[r][0] += av * w.x; acc[r][1] += av * w.y;
            acc[r][2] += av * w.z; acc[r][3] += av * w.w;
          }
        }
      }
    }
    float4 bv = make_float4(0.f, 0.f, 0.f, 0.f);
    if (cg == 0) bv = *(const float4*)&q_b[c0];
#pragma unroll
    for (int r = 0; r < 8; ++r) {
      float4 o;
      o.x = acc[r][0] + bv.x; o.y = acc[r][1] + bv.y;
      o.z = acc[r][2] + bv.z; o.w = acc[r][3] + bv.w;
      const size_t row = (size_t)(row0 + r0 + r);
      if (cg == 0) *(float4*)&q[row * CAc + c0] = o;
      else         *(float4*)&kv[row * 2 * CAc + woff + c0] = o;
    }
  }
}

// ---------------- K4: fused windowed attention v2 --------------------------
// One head's f32 score tile in LDS; atompair bias held in regs (bf16x2);
// 39.9 KB LDS + <=128 VGPR -> 4 blocks/CU.
__global__ __launch_bounds__(256, 4) void k_attn2(
    const float* __restrict__ qG, const float* __restrict__ kvG,
    const float* __restrict__ ap, const float* __restrict__ bw,
    const float* __restrict__ bb, const float* __restrict__ bW,
    const int* __restrict__ idxG, const float* __restrict__ SgG,
    const float* __restrict__ pmask, const float* __restrict__ atomF,
    float* __restrict__ atomO) {
  __shared__ float scf[WQc][129];   // 16.5 KB  (stride 129 -> conflict-free)
  __shared__ float kvb[WKc][36];    // 18.4 KB  (K, then V, current head)
  __shared__ float qb[WQc][36];     // 4.6 KB
  __shared__ float bws[CPc], bbs[CPc], bWs[CPc * Hc];
  const int tid = threadIdx.x;
  const int bwid = blockIdx.x;
  const int b = bwid >> 9, w = bwid & 511;
  if (tid < CPc) { bws[tid] = bw[tid]; bbs[tid] = bb[tid]; }
  if (tid >= 64 && tid < 64 + CPc * Hc) bWs[tid - 64] = bW[tid - 64];
  __syncthreads();

  // Phase A: atompair LN -> per-head bias (+ validity mask), kept in regs.
  unsigned bpk[16][2];  // [u][h-pair], bf16x2
  const float* apw = ap + (size_t)bwid * WQc * WKc * CPc;
#pragma unroll
  for (int u = 0; u < 16; ++u) {
    const int i = tid + 256 * u;
    const int kk = i & 127;
    const float* p = apw + (size_t)i * CPc;
    float x[16];
    float s = 0.f;
#pragma unroll
    for (int t = 0; t < 4; ++t) {
      const float4 v4 = *(const float4*)&p[t * 4];
      x[4 * t] = v4.x; x[4 * t + 1] = v4.y; x[4 * t + 2] = v4.z; x[4 * t + 3] = v4.w;
      s += v4.x + v4.y + v4.z + v4.w;
    }
    const float mn = s * (1.0f / CPc);
    float vq = 0.f;
#pragma unroll
    for (int t = 0; t < 16; ++t) { const float d = x[t] - mn; vq += d * d; }
    const float rs = rsqrtf(vq * (1.0f / CPc) + EPSf);
    float bh[4] = {0.f, 0.f, 0.f, 0.f};
#pragma unroll
    for (int cp = 0; cp < 16; ++cp) {
      const float yv = (x[cp] - mn) * rs * bws[cp] + bbs[cp];
      bh[0] += yv * bWs[cp * 4 + 0]; bh[1] += yv * bWs[cp * 4 + 1];
      bh[2] += yv * bWs[cp * 4 + 2]; bh[3] += yv * bWs[cp * 4 + 3];
    }
    const int gk = w * 32 - 48 + kk;
    const float maskt = (gk >= 0 && gk < Nc) ? 0.f : NEG_INF;
    bpk[u][0] = pk2(bh[0] + maskt, bh[1] + maskt);
    bpk[u][1] = pk2(bh[2] + maskt, bh[3] + maskt);
  }

#pragma unroll
  for (int h = 0; h < Hc; ++h) {
    // bias h -> scf
#pragma unroll
    for (int u = 0; u < 16; ++u) {
      const int i = tid + 256 * u;
      scf[i >> 7][i & 127] = unpk(bpk[u][h >> 1], h & 1);
    }
    // q load (256 float4)
    {
      const int rr = tid >> 3, cc = (tid & 7) * 4;
      *(float4*)&qb[rr][cc] =
          *(const float4*)&qG[((size_t)(b * Nc + w * 32 + rr)) * CAc + h * 32 + cc];
    }
    // K load (1024 float4)
#pragma unroll
    for (int u = 0; u < 4; ++u) {
      const int i = tid + 256 * u;
      const int rr = i >> 3, cc = (i & 7) * 4;
      int gk = w * 32 - 48 + rr;
      gk = min(max(gk, 0), Nc - 1);
      *(float4*)&kvb[rr][cc] =
          *(const float4*)&kvG[((size_t)(b * Nc + gk)) * (2 * CAc) + h * 32 + cc];
    }
    __syncthreads();
    // QK^T: RMW into scf
    {
      const int qq = tid & 31, kg = tid >> 5;
      float4 qv[8];
#pragma unroll
      for (int j = 0; j < 8; ++j) qv[j] = *(const float4*)&qb[qq][j * 4];
#pragma unroll
      for (int k2 = 0; k2 < 16; ++k2) {
        const int kk = kg * 16 + k2;
        float acc = 0.f;
#pragma unroll
        for (int j = 0; j < 8; ++j) {
          const float4 kv4 = *(const float4*)&kvb[kk][j * 4];
          acc += qv[j].x * kv4.x + qv[j].y * kv4.y + qv[j].z * kv4.z + qv[j].w * kv4.w;
        }
        scf[qq][kk] += acc * QK_SCALE;
      }
    }
    __syncthreads();
    // V prefetch to regs (hides HBM under softmax)
    float4 vreg[4];
#pragma unroll
    for (int u = 0; u < 4; ++u) {
      const int i = tid + 256 * u;
      const int rr = i >> 3, cc = (i & 7) * 4;
      int gk = w * 32 - 48 + rr;
      gk = min(max(gk, 0), Nc - 1);
      vreg[u] = *(const float4*)&kvG[((size_t)(b * Nc + gk)) * (2 * CAc) + CAc + h * 32 + cc];
    }
    // softmax (f32 in scf), 8 threads per row
    {
      const int qq = tid >> 3, kg = tid & 7;
      float vals[16];
      float mx = -3e38f;
#pragma unroll
      for (int k2 = 0; k2 < 16; ++k2) {
        vals[k2] = scf[qq][kg * 16 + k2];
        mx = fmaxf(mx, vals[k2]);
      }
#pragma unroll
      for (int mk = 1; mk <= 4; mk <<= 1) mx = fmaxf(mx, __shfl_xor(mx, mk, 64));
      float sm = 0.f;
#pragma unroll
      for (int k2 = 0; k2 < 16; ++k2) { vals[k2] = __expf(vals[k2] - mx); sm += vals[k2]; }
#pragma unroll
      for (int mk = 1; mk <= 4; mk <<= 1) sm += __shfl_xor(sm, mk, 64);
      const float inv = 1.0f / sm;
#pragma unroll
      for (int k2 = 0; k2 < 16; ++k2) scf[qq][kg * 16 + k2] = vals[k2] * inv;
    }
    // V regs -> LDS (K reads finished at the post-QK^T barrier)
#pragma unroll
    for (int u = 0; u < 4; ++u) {
      const int i = tid + 256 * u;
      *(float4*)&kvb[i >> 3][(i & 7) * 4] = vreg[u];
    }
    __syncthreads();
    // PV + gated residual epilogue
    {
      const int qq = tid >> 3, dg = tid & 7;
      float4 acc = make_float4(0.f, 0.f, 0.f, 0.f);
      for (int kk = 0; kk < WKc; ++kk) {
        const float p = scf[qq][kk];
        const float4 v4 = *(const float4*)&kvb[kk][dg * 4];
        acc.x += p * v4.x; acc.y += p * v4.y; acc.z += p * v4.z; acc.w += p * v4.w;
      }
      const int n = w * 32 + qq;
      const int c = h * 32 + dg * 4;
      const int rowg = b * Nc + n;
      const int idx = idxG[rowg];
      const float4 g4 = *(const float4*)&SgG[(size_t)(b * Rc + idx) * CAc + c];
      const float pm = pmask[rowg];
      const float4 af = *(const float4*)&atomF[(size_t)rowg * CAc + c];
      float4 o;
      o.x = af.x + acc.x * g4.x * pm; o.y = af.y + acc.y * g4.y * pm;
      o.z = af.z + acc.z * g4.z * pm; o.w = af.w + acc.w * g4.w * pm;
      *(float4*)&atomO[(size_t)rowg * CAc + c] = o;
    }
    __syncthreads();
  }
}

// ---------------- K6: transition part 1 (silu(t@W1)*(t@W2)) ---------------
__global__ void k_trans1(const float* __restrict__ t, const float* __restrict__ W1,
                         const float* __restrict__ W2, float* __restrict__ bmid) {
  __shared__ float tile[32 * CAc];
  const int row0 = blockIdx.x * 32;
  const int ct = blockIdx.y;  // col half of 256
  const float4* src = (const float4*)(t + (size_t)row0 * CAc);
  float4* dst = (float4*)tile;
#pragma unroll
  for (int k = 0; k < 4; ++k) dst[threadIdx.x + 256 * k] = src[threadIdx.x + 256 * k];
  __syncthreads();
  const int c0 = (threadIdx.x & 31) * 4;
  const int r0 = (threadIdx.x >> 5) * 4;
  const int cc = ct * 128 + c0;
  float acc1[4][4] = {}, acc2[4][4] = {};
  for (int j = 0; j < CAc; j += 4) {
    float4 a[4];
#pragma unroll
    for (int r = 0; r < 4; ++r) a[r] = *(const float4*)&tile[(r0 + r) * CAc + j];
#pragma unroll
    for (int jj = 0; jj < 4; ++jj) {
      const float4 w1 = *(const float4*)&W1[(size_t)(j + jj) * 256 + cc];
      const float4 w2 = *(const float4*)&W2[(size_t)(j + jj) * 256 + cc];
#pragma unroll
      for (int r = 0; r < 4; ++r) {
        const float av = f4c(a[r], jj);
        acc1[r][0] += av * w1.x; acc1[r][1] += av * w1.y;
        acc1[r][2] += av * w1.z; acc1[r][3] += av * w1.w;
        acc2[r][0] += av * w2.x; acc2[r][1] += av * w2.y;
        acc2[r][2] += av * w2.z; acc2[r][3] += av * w2.w;
      }
    }
  }
#pragma unroll
  for (int r = 0; r < 4; ++r) {
    float4 o;
    o.x = acc1[r][0] * sigm(acc1[r][0]) * acc2[r][0];
    o.y = acc1[r][1] * sigm(acc1[r][1]) * acc2[r][1];
    o.z = acc1[r][2] * sigm(acc1[r][2]) * acc2[r][2];
    o.w = acc1[r][3] * sigm(acc1[r][3]) * acc2[r][3];
    *(float4*)&bmid[(size_t)(row0 + r0 + r) * 256 + cc] = o;
  }
}

// ---------------- K7: transition part 2 + final residual -------------------
__global__ void k_trans2(const float* __restrict__ bm, const float* __restrict__ Wo,
                         const float* __restrict__ atomw, const int* __restrict__ idxG,
                         const float* __restrict__ TcG, const float* __restrict__ pmask,
                         float* __restrict__ outG) {
  __shared__ float tile[32 * 256];
  const int row0 = blockIdx.x * 32;
  const float4* src = (const float4*)(bm + (size_t)row0 * 256);
  float4* dst = (float4*)tile;
#pragma unroll
  for (int k = 0; k < 8; ++k) dst[threadIdx.x + 256 * k] = src[threadIdx.x + 256 * k];
  __syncthreads();
  const int c0 = (threadIdx.x & 31) * 4;
  const int r0 = (threadIdx.x >> 5) * 4;
  float acc[4][4] = {};
  for (int j = 0; j < 256; j += 4) {
    float4 a[4];
#pragma unroll
    for (int r = 0; r < 4; ++r) a[r] = *(const float4*)&tile[(r0 + r) * 256 + j];
#pragma unroll
    for (int jj = 0; jj < 4; ++jj) {
      const float4 w = *(const float4*)&Wo[(size_t)(j + jj) * CAc + c0];
#pragma unroll
      for (int r = 0; r < 4; ++r) {
        const float av = f4c(a[r], jj);
        acc[r][0] += av * w.x; acc[r][1] += av * w.y;
        acc[r][2] += av * w.z; acc[r][3] += av * w.w;
      }
    }
  }
#pragma unroll
  for (int r = 0; r < 4; ++r) {
    const int row = row0 + r0 + r;
    const int b = row >> 14;
    const int idx = idxG[row];
    const float pm = pmask[row];
    const float4 tc = *(const float4*)&TcG[(size_t)(b * Rc + idx) * CAc + c0];
    const float4 at = *(const float4*)&atomw[(size_t)row * CAc + c0];
    float4 o;
    o.x = at.x + tc.x * acc[r][0] * pm; o.y = at.y + tc.y * acc[r][1] * pm;
    o.z = at.z + tc.z * acc[r][2] * pm; o.w = at.w + tc.w * acc[r][3] * pm;
    *(float4*)&outG[(size_t)row * CAc + c0] = o;
  }
}

}  // namespace

extern "C" void kernel_launch(void* const* d_in, const int* in_sizes, int n_in,
                              void* d_out, int out_size, void* d_ws, size_t ws_size,
                              hipStream_t stream) {
  (void)in_sizes; (void)n_in; (void)out_size; (void)ws_size;
  const float* atomF   = (const float*)d_in[0];
  const float* resF    = (const float*)d_in[1];
  const float* apF     = (const float*)d_in[2];
  const int*   idx     = (const int*)d_in[3];
  const float* pmask   = (const float*)d_in[4];
  // d_in[5] atompair_mask: validity recomputed in-kernel
  const float* a_ln_w  = (const float*)d_in[6];
  const float* a_Wg    = (const float*)d_in[7];
  const float* a_bg    = (const float*)d_in[8];
  const float* a_Wb    = (const float*)d_in[9];
  const float* q_W     = (const float*)d_in[10];
  const float* q_b     = (const float*)d_in[11];
  const float* kv_W    = (const float*)d_in[12];
  const float* bij_ln_w= (const float*)d_in[13];
  const float* bij_ln_b= (const float*)d_in[14];
  const float* bij_W   = (const float*)d_in[15];
  const float* sg_W    = (const float*)d_in[16];
  const float* sg_b    = (const float*)d_in[17];
  const float* t_ln_w  = (const float*)d_in[18];
  const float* t_Wg    = (const float*)d_in[19];
  const float* t_bg    = (const float*)d_in[20];
  const float* t_Wb    = (const float*)d_in[21];
  const float* t_W1    = (const float*)d_in[22];
  const float* t_W2    = (const float*)d_in[23];
  const float* t_Wc    = (const float*)d_in[24];
  const float* t_bc    = (const float*)d_in[25];
  const float* t_Wo    = (const float*)d_in[26];

  float* ws    = (float*)d_ws;
  float* Ag    = ws;                      // B*R*CA = 524288 each
  float* Ab    = Ag + 524288;
  float* Tg    = Ab + 524288;
  float* Tb    = Tg + 524288;
  float* Sg    = Tb + 524288;
  float* Tc    = Sg + 524288;
  float* lnA   = Tc + 524288;             // B*R*CS = 1048576 each
  float* lnT   = lnA + 1048576;
  float* sbuf  = lnT + 1048576;           // B*N*CA = 4194304  (s, later t)
  float* qbuf  = sbuf + 4194304;          // B*N*CA
  float* kvbuf = qbuf + 4194304;          // B*N*2CA = 8388608
  float* atomw = kvbuf + 8388608;         // B*N*CA
  float* bmid  = qbuf;                    // reuse q+kv region after attention

  k_res_ln<<<dim3(Bc * Rc / 4), dim3(256), 0, stream>>>(resF, a_ln_w, t_ln_w, lnA, lnT);
  k_res_gemm<<<dim3(Bc * Rc / 32, 6), dim3(256), 0, stream>>>(
      lnA, lnT, resF, a_Wg, a_bg, a_Wb, t_Wg, t_bg, t_Wb, sg_W, sg_b, t_Wc, t_bc,
      Ag, Ab, Tg, Tb, Sg, Tc);
  k_adaln<<<dim3(Bc * Nc / 4), dim3(256), 0, stream>>>(atomF, idx, Ag, Ab, sbuf);
  k_qkv2<<<dim3(Bc * Nc / 64), dim3(256), 0, stream>>>(sbuf, q_W, q_b, kv_W, qbuf, kvbuf);
  k_attn2<<<dim3(Bc * NWc), dim3(256), 0, stream>>>(qbuf, kvbuf, apF, bij_ln_w, bij_ln_b,
                                                    bij_W, idx, Sg, pmask, atomF, atomw);
  k_adaln<<<dim3(Bc * Nc / 4), dim3(256), 0, stream>>>(atomw, idx, Tg, Tb, sbuf);
  k_trans1<<<dim3(Bc * Nc / 32, 2), dim3(256), 0, stream>>>(sbuf, t_W1, t_W2, bmid);
  k_trans2<<<dim3(Bc * Nc / 32), dim3(256), 0, stream>>>(bmid, t_Wo, atomw, idx, Tc, pmask,
                                                         (float*)d_out);
}

// Round 4
// 464.234 us; speedup vs baseline: 2.0397x; 2.0397x over previous
//
#include <hip/hip_runtime.h>
#include <hip/hip_bf16.h>
#include <string.h>

namespace {

constexpr int Bc  = 2;
constexpr int Nc  = 16384;
constexpr int Rc  = 2048;
constexpr int CAc = 128;
constexpr int CSc = 256;
constexpr int CPc = 16;
constexpr int Hc  = 4;
constexpr int WQc = 32;
constexpr int WKc = 128;
constexpr int NWc = 512;
constexpr int CHc = 32;
constexpr float EPSf     = 1e-5f;
constexpr float NEG_INF  = -1e8f;
constexpr float QK_SCALE = 0.17677669529663687f;  // 1/sqrt(32)

typedef short bf16x8 __attribute__((ext_vector_type(8)));
typedef float f32x4 __attribute__((ext_vector_type(4)));
typedef int   i32x4 __attribute__((ext_vector_type(4)));
typedef unsigned int u32x4 __attribute__((ext_vector_type(4)));

__device__ __forceinline__ float wsum(float v) {
#pragma unroll
  for (int m = 1; m < 64; m <<= 1) v += __shfl_xor(v, m, 64);
  return v;
}
__device__ __forceinline__ float sigm(float x) { return 1.0f / (1.0f + __expf(-x)); }
__device__ __forceinline__ float f4c(const float4& v, int i) {
  return i == 0 ? v.x : i == 1 ? v.y : i == 2 ? v.z : v.w;
}
__device__ __forceinline__ unsigned short bfx(float v) {
  __hip_bfloat16 h = __float2bfloat16(v);
  unsigned short u;
  memcpy(&u, &h, 2);
  return u;
}
__device__ __forceinline__ unsigned pk2(float a, float b) {
  return (unsigned)bfx(a) | ((unsigned)bfx(b) << 16);
}

// ---------------- K1a: per-res LN (two weighted variants) ----------------
__global__ void k_res_ln(const float* __restrict__ res, const float* __restrict__ a_ln_w,
                         const float* __restrict__ t_ln_w, float* __restrict__ lnA,
                         float* __restrict__ lnT) {
  const int wid = threadIdx.x >> 6, lane = threadIdx.x & 63;
  const int row = blockIdx.x * 4 + wid;  // B*R rows
  const float* r = res + (size_t)row * CSc;
  float x[4], s = 0.f, sq = 0.f;
#pragma unroll
  for (int i = 0; i < 4; ++i) { x[i] = r[lane + 64 * i]; s += x[i]; sq += x[i] * x[i]; }
  s = wsum(s); sq = wsum(sq);
  const float mn = s * (1.0f / CSc);
  const float var = sq * (1.0f / CSc) - mn * mn;
  const float rs = rsqrtf(var + EPSf);
#pragma unroll
  for (int i = 0; i < 4; ++i) {
    const int c = lane + 64 * i;
    const float y = (x[i] - mn) * rs;
    lnA[(size_t)row * CSc + c] = y * a_ln_w[c];
    lnT[(size_t)row * CSc + c] = y * t_ln_w[c];
  }
}

// ---------------- K1b: 6 res GEMMs (K=256 -> 128 cols), gates sigmoid'd ----
__global__ void k_res_gemm(const float* __restrict__ lnA, const float* __restrict__ lnT,
                           const float* __restrict__ res,
                           const float* __restrict__ a_Wg, const float* __restrict__ a_bg,
                           const float* __restrict__ a_Wb,
                           const float* __restrict__ t_Wg, const float* __restrict__ t_bg,
                           const float* __restrict__ t_Wb,
                           const float* __restrict__ sg_W, const float* __restrict__ sg_b,
                           const float* __restrict__ t_Wc, const float* __restrict__ t_bc,
                           float* __restrict__ Ag, float* __restrict__ Ab,
                           float* __restrict__ Tg, float* __restrict__ Tb,
                           float* __restrict__ Sg, float* __restrict__ Tc) {
  __shared__ float tile[32 * CSc];
  const int m = blockIdx.y;
  const float* in = (m < 2) ? lnA : (m < 4) ? lnT : res;
  const float* W  = (m == 0) ? a_Wg : (m == 1) ? a_Wb : (m == 2) ? t_Wg
                  : (m == 3) ? t_Wb : (m == 4) ? sg_W : t_Wc;
  const float* bias = (m == 0) ? a_bg : (m == 2) ? t_bg : (m == 4) ? sg_b
                    : (m == 5) ? t_bc : nullptr;
  const bool sig = (m == 0) || (m == 2) || (m == 4) || (m == 5);
  float* out = (m == 0) ? Ag : (m == 1) ? Ab : (m == 2) ? Tg
             : (m == 3) ? Tb : (m == 4) ? Sg : Tc;
  const int row0 = blockIdx.x * 32;
  const float4* src = (const float4*)(in + (size_t)row0 * CSc);
  float4* dst = (float4*)tile;
#pragma unroll
  for (int k = 0; k < 8; ++k) dst[threadIdx.x + 256 * k] = src[threadIdx.x + 256 * k];
  __syncthreads();
  const int c0 = (threadIdx.x & 31) * 4;
  const int r0 = (threadIdx.x >> 5) * 4;
  float acc[4][4] = {};
  for (int j = 0; j < CSc; j += 4) {
    float4 a[4];
#pragma unroll
    for (int r = 0; r < 4; ++r) a[r] = *(const float4*)&tile[(r0 + r) * CSc + j];
#pragma unroll
    for (int jj = 0; jj < 4; ++jj) {
      const float4 w = *(const float4*)&W[(size_t)(j + jj) * CAc + c0];
#pragma unroll
      for (int r = 0; r < 4; ++r) {
        const float av = f4c(a[r], jj);
        acc[r][0] += av * w.x; acc[r][1] += av * w.y;
        acc[r][2] += av * w.z; acc[r][3] += av * w.w;
      }
    }
  }
  float4 bv = make_float4(0.f, 0.f, 0.f, 0.f);
  if (bias) bv = *(const float4*)&bias[c0];
#pragma unroll
  for (int r = 0; r < 4; ++r) {
    float4 o;
    o.x = acc[r][0] + bv.x; o.y = acc[r][1] + bv.y;
    o.z = acc[r][2] + bv.z; o.w = acc[r][3] + bv.w;
    if (sig) { o.x = sigm(o.x); o.y = sigm(o.y); o.z = sigm(o.z); o.w = sigm(o.w); }
    *(float4*)&out[(size_t)(row0 + r0 + r) * CAc + c0] = o;
  }
}

// ---------------- K2/K5: adaLN over atoms (row LN 128 + gather gate/bias) --
__global__ void k_adaln(const float* __restrict__ in, const int* __restrict__ idxG,
                        const float* __restrict__ G, const float* __restrict__ Bb,
                        float* __restrict__ out) {
  const int wid = threadIdx.x >> 6, lane = threadIdx.x & 63;
  const int row = blockIdx.x * 4 + wid;  // B*N rows
  const int b = row >> 14;
  const float* r = in + (size_t)row * CAc;
  const float x0 = r[lane], x1 = r[lane + 64];
  const float s = wsum(x0 + x1);
  const float sq = wsum(x0 * x0 + x1 * x1);
  const float mn = s * (1.0f / CAc);
  const float var = sq * (1.0f / CAc) - mn * mn;
  const float rs = rsqrtf(var + EPSf);
  const int base = (b * Rc + idxG[row]) * CAc;
  out[(size_t)row * CAc + lane]      = (x0 - mn) * rs * G[base + lane]      + Bb[base + lane];
  out[(size_t)row * CAc + lane + 64] = (x1 - mn) * rs * G[base + lane + 64] + Bb[base + lane + 64];
}

// ---------------- K3: q/kv projection GEMM -> bf16 outputs -----------------
// q is pre-scaled by 1/sqrt(CH). W chunks staged in LDS (R1 fix).
__global__ __launch_bounds__(256) void k_qkv3(
    const float* __restrict__ s, const float* __restrict__ q_W,
    const float* __restrict__ q_b, const float* __restrict__ kv_W,
    ushort* __restrict__ q, ushort* __restrict__ kv) {
  __shared__ float stile[64 * CAc];   // 32 KB
  __shared__ float wbuf[32 * 132];    // 16.5 KB
  const int tid = threadIdx.x;
  const int row0 = blockIdx.x * 64;
  {
    const float4* src = (const float4*)(s + (size_t)row0 * CAc);
    float4* dst = (float4*)stile;
#pragma unroll
    for (int k = 0; k < 8; ++k) dst[tid + 256 * k] = src[tid + 256 * k];
  }
  const int c0 = (tid & 31) * 4;
  const int r0 = (tid >> 5) * 8;
#pragma unroll
  for (int cg = 0; cg < 3; ++cg) {
    const float* W  = (cg == 0) ? q_W : kv_W;
    const int wld   = (cg == 0) ? CAc : 2 * CAc;
    const int woff  = (cg == 2) ? CAc : 0;
    float acc[8][4] = {};
    for (int kc = 0; kc < 4; ++kc) {
      __syncthreads();
#pragma unroll
      for (int u = 0; u < 4; ++u) {
        const int i = tid + 256 * u;
        const int rr = i >> 5, cc = i & 31;
        *(float4*)&wbuf[rr * 132 + cc * 4] =
            *(const float4*)&W[(size_t)(kc * 32 + rr) * wld + woff + cc * 4];
      }
      __syncthreads();
      for (int j4 = 0; j4 < 8; ++j4) {
        float4 a[8];
#pragma unroll
        for (int r = 0; r < 8; ++r)
          a[r] = *(const float4*)&stile[(r0 + r) * CAc + kc * 32 + j4 * 4];
#pragma unroll
        for (int jj = 0; jj < 4; ++jj) {
          const float4 w = *(const float4*)&wbuf[(j4 * 4 + jj) * 132 + c0];
#pragma unroll
          for (int r = 0; r < 8; ++r) {
            const float av = f4c(a[r], jj);
            acc[r][0] += av * w.x; acc[r][1] += av * w.y;
            acc[r][2] += av * w.z; acc[r][3] += av * w.w;
          }
        }
      }
    }
    float4 bv = make_float4(0.f, 0.f, 0.f, 0.f);
    if (cg == 0) bv = *(const float4*)&q_b[c0];
#pragma unroll
    for (int r = 0; r < 8; ++r) {
      float4 o;
      o.x = acc[r][0] + bv.x; o.y = acc[r][1] + bv.y;
      o.z = acc[r][2] + bv.z; o.w = acc[r][3] + bv.w;
      const size_t row = (size_t)(row0 + r0 + r);
      ushort4 u4;
      if (cg == 0) {
        u4.x = bfx(o.x * QK_SCALE); u4.y = bfx(o.y * QK_SCALE);
        u4.z = bfx(o.z * QK_SCALE); u4.w = bfx(o.w * QK_SCALE);
        *(ushort4*)&q[row * CAc + c0] = u4;
      } else {
        u4.x = bfx(o.x); u4.y = bfx(o.y); u4.z = bfx(o.z); u4.w = bfx(o.w);
        *(ushort4*)&kv[row * 2 * CAc + woff + c0] = u4;
      }
    }
  }
}

// ---------------- K4: MFMA windowed attention, wave-per-head, no LDS -------
// S^T = mfma(K, q^T) with bias precomputed into the C-layout accumulator;
// in-register softmax (column-local); ds_bpermute exchange -> PV mfma.
// C/D layout (verified): col = lane&15, row = (lane>>4)*4 + reg.
// A/B k-slots use the identical lane->k convention, so the HW k-permutation
// cancels between operands.
__global__ __launch_bounds__(256) void k_attn3(
    const ushort* __restrict__ qG, const ushort* __restrict__ kvG,
    const float* __restrict__ ap, const float* __restrict__ bw,
    const float* __restrict__ bb, const float* __restrict__ bW,
    const int* __restrict__ idxG, const float* __restrict__ SgG,
    const float* __restrict__ pmask, const float* __restrict__ atomF,
    float* __restrict__ atomO) {
  const int tid = threadIdx.x;
  const int h = tid >> 6;           // wave == head
  const int lane = tid & 63;
  const int c = lane & 15, s = lane >> 4;
  const int bwid = blockIdx.x;
  const int b = bwid >> 9, w = bwid & 511;
  const size_t bN = (size_t)b * Nc;

  // fold atompair-LN weights for this head:
  // bias_h = rs*(x.w2 - mn*W2s) + Cb  with w2 = bij_ln_w * bij_W[:,h]
  float w2[16];
  float W2s = 0.f, Cb = 0.f;
#pragma unroll
  for (int cp = 0; cp < 16; ++cp) {
    const float bWv = bW[cp * 4 + h];
    w2[cp] = bw[cp] * bWv;
    W2s += w2[cp];
    Cb += bb[cp] * bWv;
  }

  // ---- Phase A: bias directly into mfma accumulators (S^T layout) ----
  f32x4 acc[8][2];
  const float* apw = ap + (size_t)bwid * (WQc * WKc * CPc);
#pragma unroll
  for (int mt = 0; mt < 8; ++mt) {
#pragma unroll
    for (int r = 0; r < 4; ++r) {
      const int kk = mt * 16 + 4 * s + r;
      const int gk = w * 32 - 48 + kk;
      const float maskt = (gk >= 0 && gk < Nc) ? 0.f : NEG_INF;
#pragma unroll
      for (int ntq = 0; ntq < 2; ++ntq) {
        const int qq = ntq * 16 + c;
        const float* p = apw + (size_t)(qq * 128 + kk) * 16;
        float sum = 0.f, sq = 0.f, dot = 0.f;
#pragma unroll
        for (int t = 0; t < 4; ++t) {
          const float4 v4 = *(const float4*)&p[t * 4];
          sum += v4.x + v4.y + v4.z + v4.w;
          sq += v4.x * v4.x + v4.y * v4.y + v4.z * v4.z + v4.w * v4.w;
          dot += v4.x * w2[4 * t] + v4.y * w2[4 * t + 1] +
                 v4.z * w2[4 * t + 2] + v4.w * w2[4 * t + 3];
        }
        const float mn = sum * 0.0625f;
        const float var = sq * 0.0625f - mn * mn;
        const float rs = rsqrtf(var + EPSf);
        acc[mt][ntq][r] = rs * (dot - mn * W2s) + Cb + maskt;
      }
    }
  }

  // ---- QK^T (S^T form): A = K rows, B = q^T ----
  bf16x8 bfragQ[2];
#pragma unroll
  for (int ntq = 0; ntq < 2; ++ntq) {
    const int qq = w * 32 + ntq * 16 + c;
    bfragQ[ntq] =
        __builtin_bit_cast(bf16x8, *(const u32x4*)&qG[(bN + qq) * CAc + h * 32 + 8 * s]);
  }
#pragma unroll
  for (int mt = 0; mt < 8; ++mt) {
    int gk = w * 32 - 48 + mt * 16 + c;
    gk = min(max(gk, 0), Nc - 1);
    const bf16x8 afragK =
        __builtin_bit_cast(bf16x8, *(const u32x4*)&kvG[(bN + gk) * 256 + h * 32 + 8 * s]);
#pragma unroll
    for (int ntq = 0; ntq < 2; ++ntq)
      acc[mt][ntq] = __builtin_amdgcn_mfma_f32_16x16x32_bf16(afragK, bfragQ[ntq],
                                                             acc[mt][ntq], 0, 0, 0);
  }

  // ---- softmax over k (in-lane 32 values + xor16/xor32), pack to bf16 ----
  int ppk[8][2][2];
#pragma unroll
  for (int ntq = 0; ntq < 2; ++ntq) {
    float mx = -3e38f;
#pragma unroll
    for (int mt = 0; mt < 8; ++mt)
#pragma unroll
      for (int r = 0; r < 4; ++r) mx = fmaxf(mx, acc[mt][ntq][r]);
    mx = fmaxf(mx, __shfl_xor(mx, 16, 64));
    mx = fmaxf(mx, __shfl_xor(mx, 32, 64));
    float sm = 0.f;
#pragma unroll
    for (int mt = 0; mt < 8; ++mt)
#pragma unroll
      for (int r = 0; r < 4; ++r) {
        const float e = __expf(acc[mt][ntq][r] - mx);
        acc[mt][ntq][r] = e;
        sm += e;
      }
    sm += __shfl_xor(sm, 16, 64);
    sm += __shfl_xor(sm, 32, 64);
    const float inv = 1.0f / sm;
#pragma unroll
    for (int mt = 0; mt < 8; ++mt) {
      ppk[mt][ntq][0] = (int)pk2(acc[mt][ntq][0] * inv, acc[mt][ntq][1] * inv);
      ppk[mt][ntq][1] = (int)pk2(acc[mt][ntq][2] * inv, acc[mt][ntq][3] * inv);
    }
  }

  // ---- PV: A = P (bpermute exchange), B = V (direct global bf16) ----
  f32x4 opv[2][2];
#pragma unroll
  for (int i = 0; i < 2; ++i)
#pragma unroll
    for (int j = 0; j < 2; ++j) { opv[i][j][0] = 0.f; opv[i][j][1] = 0.f; opv[i][j][2] = 0.f; opv[i][j][3] = 0.f; }
  const int idxA = 4 * ((((2 * s) & 3) << 4) | c);
  const int idxB = 4 * ((((2 * s + 1) & 3) << 4) | c);
#pragma unroll
  for (int ks = 0; ks < 4; ++ks) {
    int bv[2][4];
#pragma unroll
    for (int ntd = 0; ntd < 2; ++ntd) {
#pragma unroll
      for (int ip = 0; ip < 4; ++ip) {
        int g0 = w * 32 - 48 + ks * 32 + 8 * s + 2 * ip;
        int g1 = g0 + 1;
        g0 = min(max(g0, 0), Nc - 1);
        g1 = min(max(g1, 0), Nc - 1);
        const unsigned lo = kvG[(bN + g0) * 256 + CAc + h * 32 + ntd * 16 + c];
        const unsigned hi = kvG[(bN + g1) * 256 + CAc + h * 32 + ntd * 16 + c];
        bv[ntd][ip] = (int)(lo | (hi << 16));
      }
    }
#pragma unroll
    for (int mtp = 0; mtp < 2; ++mtp) {
      // target slot (lane, i): needs P[q = mtp*16 + c][k = ks*32 + 8s + i]
      // source reg mt' = 2ks + (s_t>>1) must be selected AFTER the gather
      // (two bpermutes, cndmask on the target lane's s).
      i32x4 at;
      {
        const int a0 = __builtin_amdgcn_ds_bpermute(idxA, ppk[2 * ks][mtp][0]);
        const int b0 = __builtin_amdgcn_ds_bpermute(idxA, ppk[2 * ks + 1][mtp][0]);
        at[0] = (s < 2) ? a0 : b0;
        const int a1 = __builtin_amdgcn_ds_bpermute(idxA, ppk[2 * ks][mtp][1]);
        const int b1 = __builtin_amdgcn_ds_bpermute(idxA, ppk[2 * ks + 1][mtp][1]);
        at[1] = (s < 2) ? a1 : b1;
        const int a2 = __builtin_amdgcn_ds_bpermute(idxB, ppk[2 * ks][mtp][0]);
        const int b2 = __builtin_amdgcn_ds_bpermute(idxB, ppk[2 * ks + 1][mtp][0]);
        at[2] = (s < 2) ? a2 : b2;
        const int a3 = __builtin_amdgcn_ds_bpermute(idxB, ppk[2 * ks][mtp][1]);
        const int b3 = __builtin_amdgcn_ds_bpermute(idxB, ppk[2 * ks + 1][mtp][1]);
        at[3] = (s < 2) ? a3 : b3;
      }
      const bf16x8 afragP = __builtin_bit_cast(bf16x8, at);
#pragma unroll
      for (int ntd = 0; ntd < 2; ++ntd) {
        const i32x4 bvv = {bv[ntd][0], bv[ntd][1], bv[ntd][2], bv[ntd][3]};
        opv[mtp][ntd] = __builtin_amdgcn_mfma_f32_16x16x32_bf16(
            afragP, __builtin_bit_cast(bf16x8, bvv), opv[mtp][ntd], 0, 0, 0);
      }
    }
  }

  // ---- epilogue: gated residual ----
#pragma unroll
  for (int mtp = 0; mtp < 2; ++mtp) {
#pragma unroll
    for (int r = 0; r < 4; ++r) {
      const int qq = w * 32 + mtp * 16 + 4 * s + r;
      const size_t rowg = bN + qq;
      const int residx = idxG[rowg];
      const float pm = pmask[rowg];
      const size_t gbase = ((size_t)b * Rc + residx) * CAc;
#pragma unroll
      for (int ntd = 0; ntd < 2; ++ntd) {
        const int d = h * 32 + ntd * 16 + c;
        const float g = SgG[gbase + d];
        const float af = atomF[rowg * CAc + d];
        atomO[rowg * CAc + d] = af + opv[mtp][ntd][r] * g * pm;
      }
    }
  }
}

// ---------------- K6: transition part 1 (silu(t@W1)*(t@W2)) ---------------
__global__ void k_trans1(const float* __restrict__ t, const float* __restrict__ W1,
                         const float* __restrict__ W2, float* __restrict__ bmid) {
  __shared__ float tile[32 * CAc];
  const int row0 = blockIdx.x * 32;
  const int ct = blockIdx.y;
  const float4* src = (const float4*)(t + (size_t)row0 * CAc);
  float4* dst = (float4*)tile;
#pragma unroll
  for (int k = 0; k < 4; ++k) dst[threadIdx.x + 256 * k] = src[threadIdx.x + 256 * k];
  __syncthreads();
  const int c0 = (threadIdx.x & 31) * 4;
  const int r0 = (threadIdx.x >> 5) * 4;
  const int cc = ct * 128 + c0;
  float acc1[4][4] = {}, acc2[4][4] = {};
  for (int j = 0; j < CAc; j += 4) {
    float4 a[4];
#pragma unroll
    for (int r = 0; r < 4; ++r) a[r] = *(const float4*)&tile[(r0 + r) * CAc + j];
#pragma unroll
    for (int jj = 0; jj < 4; ++jj) {
      const float4 w1 = *(const float4*)&W1[(size_t)(j + jj) * 256 + cc];
      const float4 w2 = *(const float4*)&W2[(size_t)(j + jj) * 256 + cc];
#pragma unroll
      for (int r = 0; r < 4; ++r) {
        const float av = f4c(a[r], jj);
        acc1[r][0] += av * w1.x; acc1[r][1] += av * w1.y;
        acc1[r][2] += av * w1.z; acc1[r][3] += av * w1.w;
        acc2[r][0] += av * w2.x; acc2[r][1] += av * w2.y;
        acc2[r][2] += av * w2.z; acc2[r][3] += av * w2.w;
      }
    }
  }
#pragma unroll
  for (int r = 0; r < 4; ++r) {
    float4 o;
    o.x = acc1[r][0] * sigm(acc1[r][0]) * acc2[r][0];
    o.y = acc1[r][1] * sigm(acc1[r][1]) * acc2[r][1];
    o.z = acc1[r][2] * sigm(acc1[r][2]) * acc2[r][2];
    o.w = acc1[r][3] * sigm(acc1[r][3]) * acc2[r][3];
    *(float4*)&bmid[(size_t)(row0 + r0 + r) * 256 + cc] = o;
  }
}

// ---------------- K7: transition part 2 + final residual -------------------
__global__ void k_trans2(const float* __restrict__ bm, const float* __restrict__ Wo,
                         const float* __restrict__ atomw, const int* __restrict__ idxG,
                         const float* __restrict__ TcG, const float* __restrict__ pmask,
                         float* __restrict__ outG) {
  __shared__ float tile[32 * 256];
  const int row0 = blockIdx.x * 32;
  const float4* src = (const float4*)(bm + (size_t)row0 * 256);
  float4* dst = (float4*)tile;
#pragma unroll
  for (int k = 0; k < 8; ++k) dst[threadIdx.x + 256 * k] = src[threadIdx.x + 256 * k];
  __syncthreads();
  const int c0 = (threadIdx.x & 31) * 4;
  const int r0 = (threadIdx.x >> 5) * 4;
  float acc[4][4] = {};
  for (int j = 0; j < 256; j += 4) {
    float4 a[4];
#pragma unroll
    for (int r = 0; r < 4; ++r) a[r] = *(const float4*)&tile[(r0 + r) * 256 + j];
#pragma unroll
    for (int jj = 0; jj < 4; ++jj) {
      const float4 w = *(const float4*)&Wo[(size_t)(j + jj) * CAc + c0];
#pragma unroll
      for (int r = 0; r < 4; ++r) {
        const float av = f4c(a[r], jj);
        acc[r][0] += av * w.x; acc[r][1] += av * w.y;
        acc[r][2] += av * w.z; acc[r][3] += av * w.w;
      }
    }
  }
#pragma unroll
  for (int r = 0; r < 4; ++r) {
    const int row = row0 + r0 + r;
    const int b = row >> 14;
    const int idx = idxG[row];
    const float pm = pmask[row];
    const float4 tc = *(const float4*)&TcG[(size_t)(b * Rc + idx) * CAc + c0];
    const float4 at = *(const float4*)&atomw[(size_t)row * CAc + c0];
    float4 o;
    o.x = at.x + tc.x * acc[r][0] * pm; o.y = at.y + tc.y * acc[r][1] * pm;
    o.z = at.z + tc.z * acc[r][2] * pm; o.w = at.w + tc.w * acc[r][3] * pm;
    *(float4*)&outG[(size_t)row * CAc + c0] = o;
  }
}

}  // namespace

extern "C" void kernel_launch(void* const* d_in, const int* in_sizes, int n_in,
                              void* d_out, int out_size, void* d_ws, size_t ws_size,
                              hipStream_t stream) {
  (void)in_sizes; (void)n_in; (void)out_size; (void)ws_size;
  const float* atomF   = (const float*)d_in[0];
  const float* resF    = (const float*)d_in[1];
  const float* apF     = (const float*)d_in[2];
  const int*   idx     = (const int*)d_in[3];
  const float* pmask   = (const float*)d_in[4];
  // d_in[5] atompair_mask: validity recomputed in-kernel
  const float* a_ln_w  = (const float*)d_in[6];
  const float* a_Wg    = (const float*)d_in[7];
  const float* a_bg    = (const float*)d_in[8];
  const float* a_Wb    = (const float*)d_in[9];
  const float* q_W     = (const float*)d_in[10];
  const float* q_b     = (const float*)d_in[11];
  const float* kv_W    = (const float*)d_in[12];
  const float* bij_ln_w= (const float*)d_in[13];
  const float* bij_ln_b= (const float*)d_in[14];
  const float* bij_W   = (const float*)d_in[15];
  const float* sg_W    = (const float*)d_in[16];
  const float* sg_b    = (const float*)d_in[17];
  const float* t_ln_w  = (const float*)d_in[18];
  const float* t_Wg    = (const float*)d_in[19];
  const float* t_bg    = (const float*)d_in[20];
  const float* t_Wb    = (const float*)d_in[21];
  const float* t_W1    = (const float*)d_in[22];
  const float* t_W2    = (const float*)d_in[23];
  const float* t_Wc    = (const float*)d_in[24];
  const float* t_bc    = (const float*)d_in[25];
  const float* t_Wo    = (const float*)d_in[26];

  float* ws    = (float*)d_ws;
  float* Ag    = ws;                      // B*R*CA = 524288 each
  float* Ab    = Ag + 524288;
  float* Tg    = Ab + 524288;
  float* Tb    = Tg + 524288;
  float* Sg    = Tb + 524288;
  float* Tc    = Sg + 524288;
  float* lnA   = Tc + 524288;             // B*R*CS = 1048576 each
  float* lnT   = lnA + 1048576;
  float* sbuf  = lnT + 1048576;           // B*N*CA floats (s, later t)
  float* qbuf  = sbuf + 4194304;          // B*N*CA slot (holds bf16 q)
  float* kvbuf = qbuf + 4194304;          // B*N*2CA slot (holds bf16 kv)
  float* atomw = kvbuf + 8388608;         // B*N*CA
  float* bmid  = qbuf;                    // reuse q+kv region after attention

  ushort* q16  = (ushort*)qbuf;
  ushort* kv16 = (ushort*)kvbuf;

  k_res_ln<<<dim3(Bc * Rc / 4), dim3(256), 0, stream>>>(resF, a_ln_w, t_ln_w, lnA, lnT);
  k_res_gemm<<<dim3(Bc * Rc / 32, 6), dim3(256), 0, stream>>>(
      lnA, lnT, resF, a_Wg, a_bg, a_Wb, t_Wg, t_bg, t_Wb, sg_W, sg_b, t_Wc, t_bc,
      Ag, Ab, Tg, Tb, Sg, Tc);
  k_adaln<<<dim3(Bc * Nc / 4), dim3(256), 0, stream>>>(atomF, idx, Ag, Ab, sbuf);
  k_qkv3<<<dim3(Bc * Nc / 64), dim3(256), 0, stream>>>(sbuf, q_W, q_b, kv_W, q16, kv16);
  k_attn3<<<dim3(Bc * NWc), dim3(256), 0, stream>>>(q16, kv16, apF, bij_ln_w, bij_ln_b,
                                                    bij_W, idx, Sg, pmask, atomF, atomw);
  k_adaln<<<dim3(Bc * Nc / 4), dim3(256), 0, stream>>>(atomw, idx, Tg, Tb, sbuf);
  k_trans1<<<dim3(Bc * Nc / 32, 2), dim3(256), 0, stream>>>(sbuf, t_W1, t_W2, bmid);
  k_trans2<<<dim3(Bc * Nc / 32), dim3(256), 0, stream>>>(bmid, t_Wo, atomw, idx, Tc, pmask,
                                                         (float*)d_out);
}